// Round 1
// baseline (187.822 us; speedup 1.0000x reference)
//
#include <hip/hip_runtime.h>
#include <hip/hip_bf16.h>
#include <math.h>

#define N_TOT   16384
#define M_EV    4096
#define IN_DIM  128
#define SPACE_D 4
#define PROP_D  64
#define K_NN    32

// ---------------------------------------------------------------------------
// Kernel 1: space = x @ Ws + bs ; prop = x @ Wp + bp
// Block = 256 threads (4 waves); each wave computes 4 rows, lane = prop col.
// x-row values are wave-uniform -> readfirstlane forces scalar (SMEM) loads,
// Wp column loads are coalesced 256B and L1-resident (Wp = 32 KB).
// ---------------------------------------------------------------------------
__global__ __launch_bounds__(256) void linear_kernel(
    const float* __restrict__ x,
    const float* __restrict__ Ws, const float* __restrict__ bs,
    const float* __restrict__ Wp, const float* __restrict__ bp,
    float* __restrict__ space, float* __restrict__ prop)
{
  const int lane = threadIdx.x & 63;
  const int wid  = threadIdx.x >> 6;
  const int r0   = __builtin_amdgcn_readfirstlane((int)blockIdx.x * 16 + wid * 4);

  const float* xr = x + (size_t)r0 * IN_DIM;

  float a0 = bp[lane];
  float a1 = a0, a2 = a0, a3 = a0;
  #pragma unroll
  for (int i = 0; i < IN_DIM; ++i) {
    const float w = Wp[i * PROP_D + lane];
    a0 = fmaf(xr[i],              w, a0);
    a1 = fmaf(xr[IN_DIM + i],     w, a1);
    a2 = fmaf(xr[2 * IN_DIM + i], w, a2);
    a3 = fmaf(xr[3 * IN_DIM + i], w, a3);
  }
  prop[(size_t)(r0 + 0) * PROP_D + lane] = a0;
  prop[(size_t)(r0 + 1) * PROP_D + lane] = a1;
  prop[(size_t)(r0 + 2) * PROP_D + lane] = a2;
  prop[(size_t)(r0 + 3) * PROP_D + lane] = a3;

  // space: lanes 0..15 -> (row r = lane>>2, col c = lane&3)
  if (lane < 16) {
    const int r = lane >> 2, c = lane & 3;
    const float* xq = x + (size_t)(r0 + r) * IN_DIM;
    float a = bs[c];
    #pragma unroll
    for (int i = 0; i < IN_DIM; ++i)
      a = fmaf(xq[i], Ws[i * SPACE_D + c], a);
    space[(size_t)(r0 + r) * SPACE_D + c] = a;
  }
}

// ---------------------------------------------------------------------------
// Kernel 2: per-row exact KNN (K=32 of 4096, within event) + weighted agg.
// Block = 512 threads = 8 waves = 8 rows; event space slab (64 KB) in LDS.
// Per wave: 64 candidates/lane in registers (fully unrolled, static indices),
// bisection on float bits for the 32-count threshold (early exit on exact 32),
// ballot-compaction in ascending index order (JAX-stable), tie fallback.
// ---------------------------------------------------------------------------
__global__ __launch_bounds__(512) void knn_kernel(
    const float4* __restrict__ space,   // [N_TOT]
    const float*  __restrict__ prop,    // [N_TOT * PROP_D]
    float*        __restrict__ out)     // [N_TOT * 2*PROP_D]
{
  const int lane = threadIdx.x & 63;
  const int wid  = threadIdx.x >> 6;              // 0..7
  const int row  = (int)blockIdx.x * 8 + wid;     // global row
  const int m0   = row & ~(M_EV - 1);             // event base row
  const int mloc = row & (M_EV - 1);

  __shared__ float4 s_sp[M_EV];                   // 64 KB
  __shared__ int    s_idx[8][K_NN];
  __shared__ float  s_dst[8][K_NN];

  // stage event slab: 4096 float4 by 512 threads
  {
    const float4* src = space + m0;
    #pragma unroll
    for (int t = 0; t < 8; ++t) {
      const int i = (int)threadIdx.x + t * 512;
      s_sp[i] = src[i];
    }
  }
  __syncthreads();

  const float4 rc = s_sp[mloc];                   // wave-uniform broadcast

  // --- distances: candidate j = lane + 64*t ---
  float d[64];
  #pragma unroll
  for (int t = 0; t < 64; ++t) {
    const float4 c = s_sp[lane + (t << 6)];
    const float dx = rc.x - c.x, dy = rc.y - c.y;
    const float dz = rc.z - c.z, dw = rc.w - c.w;
    d[t] = fmaf(dx, dx, fmaf(dy, dy, fmaf(dz, dz, dw * dw)));
    if ((t & 7) == 7) __builtin_amdgcn_sched_barrier(0);  // cap loads in flight
  }

  // --- wave max (4 partial chains to shorten dependency) ---
  float mxa = d[0], mxb = d[1], mxc = d[2], mxd = d[3];
  #pragma unroll
  for (int t = 4; t < 64; t += 4) {
    mxa = fmaxf(mxa, d[t]);     mxb = fmaxf(mxb, d[t + 1]);
    mxc = fmaxf(mxc, d[t + 2]); mxd = fmaxf(mxd, d[t + 3]);
  }
  float mx = fmaxf(fmaxf(mxa, mxb), fmaxf(mxc, mxd));
  #pragma unroll
  for (int off = 32; off; off >>= 1) mx = fmaxf(mx, __shfl_xor(mx, off));

  auto countLE = [&](float fm) {
    int c0 = 0, c1 = 0, c2 = 0, c3 = 0;
    #pragma unroll
    for (int t = 0; t < 64; t += 4) {
      c0 += (d[t]     <= fm);
      c1 += (d[t + 1] <= fm);
      c2 += (d[t + 2] <= fm);
      c3 += (d[t + 3] <= fm);
    }
    int c = (c0 + c1) + (c2 + c3);
    #pragma unroll
    for (int off = 32; off; off >>= 1) c += __shfl_xor(c, off);
    return c;                                     // total, in every lane
  };

  // --- bisection on float bit patterns (all d >= 0 -> monotone) ---
  unsigned lo = 0u, hi = __float_as_uint(mx);
  while (lo < hi) {
    const unsigned mid = (lo + hi) >> 1;
    const int c = countLE(__uint_as_float(mid));
    if (c >= K_NN) { hi = mid; if (c == K_NN) break; }
    else lo = mid + 1;
  }
  const float Tf  = __uint_as_float(hi);
  const int   cle = countLE(Tf);

  // --- collect (idx, dist) in ascending candidate-index order ---
  int base = 0;
  if (cle == K_NN) {                              // common path: exact set
    #pragma unroll
    for (int t = 0; t < 64; ++t) {
      const bool p = (d[t] <= Tf);
      const unsigned long long mk = __ballot(p);
      if (p) {
        const int pos = base + __popcll(mk & ((1ull << lane) - 1ull));
        s_idx[wid][pos] = lane + (t << 6);
        s_dst[wid][pos] = d[t];
      }
      base += __popcll(mk);
    }
  } else {                                        // rare: ties at threshold
    #pragma unroll
    for (int t = 0; t < 64; ++t) {                // strict-less first
      const bool p = (d[t] < Tf);
      const unsigned long long mk = __ballot(p);
      if (p) {
        const int pos = base + __popcll(mk & ((1ull << lane) - 1ull));
        s_idx[wid][pos] = lane + (t << 6);
        s_dst[wid][pos] = d[t];
      }
      base += __popcll(mk);
    }
    #pragma unroll
    for (int t = 0; t < 64; ++t) {                // then equals, capped
      const bool p = (d[t] == Tf);
      const unsigned long long mk = __ballot(p);
      if (p) {
        const int pos = base + __popcll(mk & ((1ull << lane) - 1ull));
        if (pos < K_NN) { s_idx[wid][pos] = lane + (t << 6); s_dst[wid][pos] = d[t]; }
      }
      base += __popcll(mk);
    }
  }
  __syncthreads();

  // --- weighted aggregation: lane = feature, loop over 32 neighbors ---
  float accm = 0.f;
  float accx = -INFINITY;
  #pragma unroll 8
  for (int n = 0; n < K_NN; ++n) {
    const int   j  = s_idx[wid][n];               // uniform LDS broadcast
    const float dd = s_dst[wid][n];
    const float w  = __expf(-10.f * dd);
    const float v  = prop[(size_t)(m0 + j) * PROP_D + lane];  // coalesced 256B
    const float wv = w * v;
    accm += wv;
    accx = fmaxf(accx, wv);
  }
  out[(size_t)row * 128 + lane]      = accm * (1.f / K_NN);
  out[(size_t)row * 128 + 64 + lane] = accx;
}

// ---------------------------------------------------------------------------
extern "C" void kernel_launch(void* const* d_in, const int* in_sizes, int n_in,
                              void* d_out, int out_size, void* d_ws, size_t ws_size,
                              hipStream_t stream) {
  const float* x  = (const float*)d_in[0];
  const float* Ws = (const float*)d_in[1];
  const float* bs = (const float*)d_in[2];
  const float* Wp = (const float*)d_in[3];
  const float* bp = (const float*)d_in[4];
  float* out = (float*)d_out;

  // workspace layout: prop [N,64] f32 (4 MB) | space [N,4] f32 (256 KB)
  float* prop  = (float*)d_ws;
  float* space = (float*)((char*)d_ws + (size_t)N_TOT * PROP_D * sizeof(float));

  linear_kernel<<<N_TOT / 16, 256, 0, stream>>>(x, Ws, bs, Wp, bp, space, prop);
  knn_kernel<<<N_TOT / 8, 512, 0, stream>>>((const float4*)space, prop, out);
}

// Round 2
// 184.872 us; speedup vs baseline: 1.0160x; 1.0160x over previous
//
#include <hip/hip_runtime.h>
#include <hip/hip_bf16.h>
#include <math.h>

#define N_TOT   16384
#define M_EV    4096
#define IN_DIM  128
#define SPACE_D 4
#define PROP_D  64
#define K_NN    32

// ---------------------------------------------------------------------------
// Kernel 1: space = x @ Ws + bs ; prop = x @ Wp + bp
// Block = 256 threads (4 waves); each wave computes 4 rows, lane = prop col.
// ---------------------------------------------------------------------------
__global__ __launch_bounds__(256) void linear_kernel(
    const float* __restrict__ x,
    const float* __restrict__ Ws, const float* __restrict__ bs,
    const float* __restrict__ Wp, const float* __restrict__ bp,
    float* __restrict__ space, float* __restrict__ prop)
{
  const int lane = threadIdx.x & 63;
  const int wid  = threadIdx.x >> 6;
  const int r0   = __builtin_amdgcn_readfirstlane((int)blockIdx.x * 16 + wid * 4);

  const float* xr = x + (size_t)r0 * IN_DIM;

  float a0 = bp[lane];
  float a1 = a0, a2 = a0, a3 = a0;
  #pragma unroll
  for (int i = 0; i < IN_DIM; ++i) {
    const float w = Wp[i * PROP_D + lane];
    a0 = fmaf(xr[i],              w, a0);
    a1 = fmaf(xr[IN_DIM + i],     w, a1);
    a2 = fmaf(xr[2 * IN_DIM + i], w, a2);
    a3 = fmaf(xr[3 * IN_DIM + i], w, a3);
  }
  prop[(size_t)(r0 + 0) * PROP_D + lane] = a0;
  prop[(size_t)(r0 + 1) * PROP_D + lane] = a1;
  prop[(size_t)(r0 + 2) * PROP_D + lane] = a2;
  prop[(size_t)(r0 + 3) * PROP_D + lane] = a3;

  if (lane < 16) {
    const int r = lane >> 2, c = lane & 3;
    const float* xq = x + (size_t)(r0 + r) * IN_DIM;
    float a = bs[c];
    #pragma unroll
    for (int i = 0; i < IN_DIM; ++i)
      a = fmaf(xq[i], Ws[i * SPACE_D + c], a);
    space[(size_t)(r0 + r) * SPACE_D + c] = a;
  }
}

// ---------------------------------------------------------------------------
// Kernel 2: per-row exact KNN (K=32 of 4096) + weighted aggregation.
// One wave per row, 4 waves/block, NO LDS (space slab is L1/L2-resident).
// Selection: bisection on float bit patterns with ballot+scalar-popcount
// counting (VALU = 64 v_cmp per iteration; popcounts co-issue on scalar pipe).
// Aggregation: iterate ballot bits, readlane the distance, gather prop with
// lane = feature. Tie case (countLE > K at threshold) handled exactly.
// ---------------------------------------------------------------------------
__global__ __launch_bounds__(256) void knn_kernel(
    const float4* __restrict__ space,   // [N_TOT]
    const float*  __restrict__ prop,    // [N_TOT * PROP_D]
    float*        __restrict__ out)     // [N_TOT * 2*PROP_D]
{
  const int lane = threadIdx.x & 63;
  const int wid  = threadIdx.x >> 6;              // 0..3
  const int row  = (int)blockIdx.x * 4 + wid;     // global row (1 wave = 1 row)
  const int m0   = row & ~(M_EV - 1);             // event base row
  const int mloc = row & (M_EV - 1);

  const float4* __restrict__ ev = space + m0;
  const float4 rc = ev[mloc];                     // wave-uniform

  // --- distances: candidate j = lane + 64*t, from global (L1/L2-hot) ---
  float d[64];
  #pragma unroll
  for (int t = 0; t < 64; ++t) {
    const float4 c = ev[lane + (t << 6)];
    const float dx = rc.x - c.x, dy = rc.y - c.y;
    const float dz = rc.z - c.z, dw = rc.w - c.w;
    d[t] = fmaf(dx, dx, fmaf(dy, dy, fmaf(dz, dz, dw * dw)));
  }

  // wave-uniform count of {d <= fm}: v_cmp -> sgpr pair, scalar popcount+add
  auto countLE = [&](float fm) -> int {
    int c = 0;
    #pragma unroll
    for (int t = 0; t < 64; ++t)
      c += (int)__popcll(__ballot(d[t] <= fm));
    return c;
  };

  // --- bisection on float bit patterns (all d >= 0 -> monotone in bits) ---
  unsigned lo = 0u, hi = 0x7F800000u;             // [0, +inf]
  int cle = M_EV;                                 // countLE(hi)
  while (lo < hi) {
    const unsigned mid = (lo + hi) >> 1;
    const int c = countLE(__uint_as_float(mid));
    if (c >= K_NN) { hi = mid; cle = c; if (c == K_NN) break; }
    else lo = mid + 1;
  }
  const float Tf = __uint_as_float(hi);           // kth distance (threshold)

  // --- aggregation: lane = feature; iterate selected candidates ---
  float accm = 0.f;
  float accx = -INFINITY;
  const float* __restrict__ pb = prop + ((size_t)m0 << 6) + lane;

  auto nbr = [&](int j, float dd) {
    const float w  = __expf(-10.f * dd);
    const float v  = pb[(size_t)j << 6];          // coalesced 256B, L2-hot
    const float wv = w * v;
    accm += wv;
    accx = fmaxf(accx, wv);
  };

  if (cle == K_NN) {                              // common path: exact set
    #pragma unroll
    for (int t = 0; t < 64; ++t) {
      unsigned long long mk = __ballot(d[t] <= Tf);
      while (mk) {
        const int b = (int)__builtin_ctzll(mk);
        mk &= mk - 1;
        const float dd = __uint_as_float(
            __builtin_amdgcn_readlane(__float_as_uint(d[t]), b));
        nbr((t << 6) + b, dd);
      }
    }
  } else {                                        // rare: ties at threshold
    int taken = 0;
    #pragma unroll
    for (int t = 0; t < 64; ++t) {                // all strict-less (< K of them)
      unsigned long long mk = __ballot(d[t] < Tf);
      while (mk) {
        const int b = (int)__builtin_ctzll(mk);
        mk &= mk - 1;
        const float dd = __uint_as_float(
            __builtin_amdgcn_readlane(__float_as_uint(d[t]), b));
        nbr((t << 6) + b, dd);
        ++taken;
      }
    }
    #pragma unroll
    for (int t = 0; t < 64; ++t) {                // equals, lowest index first
      if (taken >= K_NN) break;
      unsigned long long mk = __ballot(d[t] == Tf);
      while (mk && taken < K_NN) {
        const int b = (int)__builtin_ctzll(mk);
        mk &= mk - 1;
        nbr((t << 6) + b, Tf);
        ++taken;
      }
    }
  }

  out[(size_t)row * 128 + lane]      = accm * (1.f / K_NN);
  out[(size_t)row * 128 + 64 + lane] = accx;
}

// ---------------------------------------------------------------------------
extern "C" void kernel_launch(void* const* d_in, const int* in_sizes, int n_in,
                              void* d_out, int out_size, void* d_ws, size_t ws_size,
                              hipStream_t stream) {
  const float* x  = (const float*)d_in[0];
  const float* Ws = (const float*)d_in[1];
  const float* bs = (const float*)d_in[2];
  const float* Wp = (const float*)d_in[3];
  const float* bp = (const float*)d_in[4];
  float* out = (float*)d_out;

  // workspace layout: prop [N,64] f32 (4 MB) | space [N,4] f32 (256 KB)
  float* prop  = (float*)d_ws;
  float* space = (float*)((char*)d_ws + (size_t)N_TOT * PROP_D * sizeof(float));

  linear_kernel<<<N_TOT / 16, 256, 0, stream>>>(x, Ws, bs, Wp, bp, space, prop);
  knn_kernel<<<N_TOT / 4, 256, 0, stream>>>((const float4*)space, prop, out);
}

// Round 3
// 118.618 us; speedup vs baseline: 1.5834x; 1.5586x over previous
//
#include <hip/hip_runtime.h>
#include <hip/hip_bf16.h>
#include <math.h>

#define N_TOT   16384
#define M_EV    4096
#define IN_DIM  128
#define SPACE_D 4
#define PROP_D  64
#define K_NN    32
#define CAND_CAP 128            // candidate buffer slots per wave (2/lane)

// ---------------------------------------------------------------------------
// Kernel 1: space = x @ Ws + bs ; prop = x @ Wp + bp
// ---------------------------------------------------------------------------
__global__ __launch_bounds__(256) void linear_kernel(
    const float* __restrict__ x,
    const float* __restrict__ Ws, const float* __restrict__ bs,
    const float* __restrict__ Wp, const float* __restrict__ bp,
    float* __restrict__ space, float* __restrict__ prop)
{
  const int lane = threadIdx.x & 63;
  const int wid  = threadIdx.x >> 6;
  const int r0   = __builtin_amdgcn_readfirstlane((int)blockIdx.x * 16 + wid * 4);

  const float* xr = x + (size_t)r0 * IN_DIM;

  float a0 = bp[lane];
  float a1 = a0, a2 = a0, a3 = a0;
  #pragma unroll
  for (int i = 0; i < IN_DIM; ++i) {
    const float w = Wp[i * PROP_D + lane];
    a0 = fmaf(xr[i],              w, a0);
    a1 = fmaf(xr[IN_DIM + i],     w, a1);
    a2 = fmaf(xr[2 * IN_DIM + i], w, a2);
    a3 = fmaf(xr[3 * IN_DIM + i], w, a3);
  }
  prop[(size_t)(r0 + 0) * PROP_D + lane] = a0;
  prop[(size_t)(r0 + 1) * PROP_D + lane] = a1;
  prop[(size_t)(r0 + 2) * PROP_D + lane] = a2;
  prop[(size_t)(r0 + 3) * PROP_D + lane] = a3;

  if (lane < 16) {
    const int r = lane >> 2, c = lane & 3;
    const float* xq = x + (size_t)(r0 + r) * IN_DIM;
    float a = bs[c];
    #pragma unroll
    for (int i = 0; i < IN_DIM; ++i)
      a = fmaf(xq[i], Ws[i * SPACE_D + c], a);
    space[(size_t)(r0 + r) * SPACE_D + c] = a;
  }
}

// per-lane count of set bits of mk strictly below this lane
__device__ __forceinline__ int mbcnt64(unsigned long long mk) {
  return (int)__builtin_amdgcn_mbcnt_hi((unsigned)(mk >> 32),
           __builtin_amdgcn_mbcnt_lo((unsigned)mk, 0u));
}

// ---------------------------------------------------------------------------
// Kernel 2: per-row exact KNN (K=32 of 4096) + weighted aggregation.
// One wave per row, 4 waves/block. Single register pass over the 4096
// candidates; prune with T_ub = 32nd-smallest of the 64 per-lane minima
// (bitonic sort, straight-line); compact C in [32,128] survivors to LDS;
// exact top-32 via bit-bisection on 2 values/lane + stable tie handling.
// ---------------------------------------------------------------------------
__global__ __launch_bounds__(256, 4) void knn_kernel(
    const float4* __restrict__ space,   // [N_TOT]
    const float*  __restrict__ prop,    // [N_TOT * PROP_D]
    float*        __restrict__ out)     // [N_TOT * 2*PROP_D]
{
  const int lane = threadIdx.x & 63;
  const int wid  = threadIdx.x >> 6;              // 0..3
  const int row  = (int)blockIdx.x * 4 + wid;     // 1 wave = 1 row
  const int m0   = row & ~(M_EV - 1);
  const int mloc = row & (M_EV - 1);

  __shared__ int   s_ci[4][CAND_CAP];
  __shared__ float s_cd[4][CAND_CAP];
  __shared__ int   s_wi[4][K_NN];
  __shared__ float s_ww[4][K_NN];

  const float4* __restrict__ ev = space + m0;
  const float4 rc = ev[mloc];

  // --- pass 1: distances in regs + per-lane min (straight-line) ---
  float d[64];
  float m = INFINITY;
  #pragma unroll
  for (int t = 0; t < 64; ++t) {
    const float4 c = ev[lane + (t << 6)];
    const float dx = rc.x - c.x, dy = rc.y - c.y;
    const float dz = rc.z - c.z, dw = rc.w - c.w;
    d[t] = fmaf(dx, dx, fmaf(dy, dy, fmaf(dz, dz, dw * dw)));
    m = fminf(m, d[t]);
  }

  // --- bitonic sort of lane minima (ascending), straight-line ---
  float ms = m;
  #pragma unroll
  for (int k = 2; k <= 64; k <<= 1) {
    #pragma unroll
    for (int j = k >> 1; j > 0; j >>= 1) {
      const float o = __shfl_xor(ms, j);
      const bool keepmin = (((lane & j) == 0) == ((lane & k) == 0));
      ms = keepmin ? fminf(ms, o) : fmaxf(ms, o);
    }
  }
  const float Tub = __shfl(ms, 31);     // 32nd smallest lane-min >= true T

  // --- count survivors ---
  int C = 0;
  #pragma unroll
  for (int t = 0; t < 64; ++t)
    C += (int)__popcll(__ballot(d[t] <= Tub));

  // --- hot path: compact survivors (ascending candidate index) ---
  if (C <= CAND_CAP) {
    int base = 0;
    #pragma unroll
    for (int t = 0; t < 64; ++t) {
      const bool p = (d[t] <= Tub);
      const unsigned long long mk = __ballot(p);
      if (p) {
        const int pos = base + mbcnt64(mk);
        s_ci[wid][pos] = (t << 6) + lane;
        s_cd[wid][pos] = d[t];
      }
      base += (int)__popcll(mk);
    }
  } else {
    // --- cold exact fallback: recompute-based bisection (d[] not used) ---
    unsigned lo = 0u, hi = __float_as_uint(Tub);
    while (lo < hi) {
      const unsigned mid = (lo + hi) >> 1;
      const float fm = __uint_as_float(mid);
      int c = 0;
      for (int t = 0; t < 64; ++t) {
        const float4 cc = ev[lane + (t << 6)];
        const float dx = rc.x - cc.x, dy = rc.y - cc.y;
        const float dz = rc.z - cc.z, dw = rc.w - cc.w;
        const float dd = fmaf(dx, dx, fmaf(dy, dy, fmaf(dz, dz, dw * dw)));
        c += (int)__popcll(__ballot(dd <= fm));
      }
      if (c >= K_NN) { hi = mid; if (c == K_NN) break; }
      else lo = mid + 1;
    }
    const float T = __uint_as_float(hi);
    int base = 0;
    for (int pass = 0; pass < 2; ++pass) {     // 0: strict-less, 1: equal
      for (int t = 0; t < 64; ++t) {
        const float4 cc = ev[lane + (t << 6)];
        const float dx = rc.x - cc.x, dy = rc.y - cc.y;
        const float dz = rc.z - cc.z, dw = rc.w - cc.w;
        const float dd = fmaf(dx, dx, fmaf(dy, dy, fmaf(dz, dz, dw * dw)));
        const bool p = pass ? (dd == T) : (dd < T);
        const unsigned long long mk = __ballot(p);
        if (p) {
          const int pos = base + mbcnt64(mk);
          if (pos < CAND_CAP) { s_ci[wid][pos] = (t << 6) + lane; s_cd[wid][pos] = dd; }
        }
        base += (int)__popcll(mk);
      }
    }
    C = base < CAND_CAP ? base : CAND_CAP;
  }

  // --- tail: exact top-32 among C (<=128) candidates, 2 per lane ---
  const bool h0 = lane < C, h1 = (64 + lane) < C;
  const float v0 = h0 ? s_cd[wid][lane]      : INFINITY;
  const float v1 = h1 ? s_cd[wid][64 + lane] : INFINITY;
  const int   i0 = h0 ? s_ci[wid][lane]      : 0;
  const int   i1 = h1 ? s_ci[wid][64 + lane] : 0;

  unsigned lo = 0u, hi = __float_as_uint(Tub);
  while (lo < hi) {
    const unsigned mid = (lo + hi) >> 1;
    const float fm = __uint_as_float(mid);
    const int c = (int)__popcll(__ballot(v0 <= fm)) +
                  (int)__popcll(__ballot(v1 <= fm));
    if (c >= K_NN) { hi = mid; if (c == K_NN) break; }
    else lo = mid + 1;
  }
  const float T2 = __uint_as_float(hi);

  // stable selection: all strict-less, then lowest-position equals
  const unsigned long long mkE0 = __ballot(v0 == T2);
  const unsigned long long mkE1 = __ballot(v1 == T2);
  const int L = (int)__popcll(__ballot(v0 < T2)) +
                (int)__popcll(__ballot(v1 < T2));
  const int e = K_NN - L;                        // equals to take (>=0)
  const int nE0 = (int)__popcll(mkE0);
  const bool sel0 = (v0 < T2) || ((v0 == T2) && (mbcnt64(mkE0) < e));
  const bool sel1 = (v1 < T2) || ((v1 == T2) && (nE0 + mbcnt64(mkE1) < e));

  const float w0 = __expf(-10.f * v0);
  const float w1 = __expf(-10.f * v1);

  {
    const unsigned long long mkS0 = __ballot(sel0);
    if (sel0) {
      const int pos = mbcnt64(mkS0);
      s_wi[wid][pos] = i0; s_ww[wid][pos] = w0;
    }
    const int b0 = (int)__popcll(mkS0);
    const unsigned long long mkS1 = __ballot(sel1);
    if (sel1) {
      const int pos = b0 + mbcnt64(mkS1);
      s_wi[wid][pos] = i1; s_ww[wid][pos] = w1;
    }
  }

  // --- aggregation: lane = feature, 32 winners ---
  float accm = 0.f;
  float accx = -INFINITY;
  const float* __restrict__ pb = prop + ((size_t)m0 << 6) + lane;
  #pragma unroll 8
  for (int n = 0; n < K_NN; ++n) {
    const int   j = s_wi[wid][n];               // uniform LDS broadcast
    const float w = s_ww[wid][n];
    const float v = pb[(size_t)j << 6];         // coalesced 256B, L2-hot
    const float wv = w * v;
    accm += wv;
    accx = fmaxf(accx, wv);
  }
  out[(size_t)row * 128 + lane]      = accm * (1.f / K_NN);
  out[(size_t)row * 128 + 64 + lane] = accx;
}

// ---------------------------------------------------------------------------
extern "C" void kernel_launch(void* const* d_in, const int* in_sizes, int n_in,
                              void* d_out, int out_size, void* d_ws, size_t ws_size,
                              hipStream_t stream) {
  const float* x  = (const float*)d_in[0];
  const float* Ws = (const float*)d_in[1];
  const float* bs = (const float*)d_in[2];
  const float* Wp = (const float*)d_in[3];
  const float* bp = (const float*)d_in[4];
  float* out = (float*)d_out;

  // workspace layout: prop [N,64] f32 (4 MB) | space [N,4] f32 (256 KB)
  float* prop  = (float*)d_ws;
  float* space = (float*)((char*)d_ws + (size_t)N_TOT * PROP_D * sizeof(float));

  linear_kernel<<<N_TOT / 16, 256, 0, stream>>>(x, Ws, bs, Wp, bp, space, prop);
  knn_kernel<<<N_TOT / 4, 256, 0, stream>>>((const float4*)space, prop, out);
}

// Round 4
// 80.696 us; speedup vs baseline: 2.3275x; 1.4699x over previous
//
#include <hip/hip_runtime.h>
#include <hip/hip_bf16.h>
#include <math.h>

#define N_TOT   16384
#define M_EV    4096
#define IN_DIM  128
#define SPACE_D 4
#define PROP_D  64
#define K_NN    32
#define CAND_CAP 128            // candidate buffer slots per wave (2/lane)

// ---------------------------------------------------------------------------
// Kernel 1: space = x @ Ws + bs ; prop = x @ Wp + bp
// ---------------------------------------------------------------------------
__global__ __launch_bounds__(256) void linear_kernel(
    const float* __restrict__ x,
    const float* __restrict__ Ws, const float* __restrict__ bs,
    const float* __restrict__ Wp, const float* __restrict__ bp,
    float* __restrict__ space, float* __restrict__ prop)
{
  const int lane = threadIdx.x & 63;
  const int wid  = threadIdx.x >> 6;
  const int r0   = __builtin_amdgcn_readfirstlane((int)blockIdx.x * 16 + wid * 4);

  const float* xr = x + (size_t)r0 * IN_DIM;

  float a0 = bp[lane];
  float a1 = a0, a2 = a0, a3 = a0;
  #pragma unroll
  for (int i = 0; i < IN_DIM; ++i) {
    const float w = Wp[i * PROP_D + lane];
    a0 = fmaf(xr[i],              w, a0);
    a1 = fmaf(xr[IN_DIM + i],     w, a1);
    a2 = fmaf(xr[2 * IN_DIM + i], w, a2);
    a3 = fmaf(xr[3 * IN_DIM + i], w, a3);
  }
  prop[(size_t)(r0 + 0) * PROP_D + lane] = a0;
  prop[(size_t)(r0 + 1) * PROP_D + lane] = a1;
  prop[(size_t)(r0 + 2) * PROP_D + lane] = a2;
  prop[(size_t)(r0 + 3) * PROP_D + lane] = a3;

  if (lane < 16) {
    const int r = lane >> 2, c = lane & 3;
    const float* xq = x + (size_t)(r0 + r) * IN_DIM;
    float a = bs[c];
    #pragma unroll
    for (int i = 0; i < IN_DIM; ++i)
      a = fmaf(xq[i], Ws[i * SPACE_D + c], a);
    space[(size_t)(r0 + r) * SPACE_D + c] = a;
  }
}

// per-lane count of set bits of mk strictly below this lane
__device__ __forceinline__ int mbcnt64(unsigned long long mk) {
  return (int)__builtin_amdgcn_mbcnt_hi((unsigned)(mk >> 32),
           __builtin_amdgcn_mbcnt_lo((unsigned)mk, 0u));
}

// ---------------------------------------------------------------------------
// Kernel 2: per-row exact KNN (K=32 of 4096) + weighted aggregation.
// 512 threads = 8 waves = 8 rows; event space slab (64 KB) in LDS.
// Pass A: running per-lane min only (no d[] array -> no spill).
// Bitonic-sort the 64 lane minima -> Tub (upper bound on kth distance).
// Pass B: recompute distances from LDS (bit-identical) and ballot-compact
// survivors <= Tub to LDS. Tail: exact top-32 via bisection on 2 vals/lane
// with JAX-stable (lowest index first) tie handling.
// ---------------------------------------------------------------------------
__global__ __launch_bounds__(512) void knn_kernel(
    const float4* __restrict__ space,   // [N_TOT]
    const float*  __restrict__ prop,    // [N_TOT * PROP_D]
    float*        __restrict__ out)     // [N_TOT * 2*PROP_D]
{
  const int lane = threadIdx.x & 63;
  const int wid  = threadIdx.x >> 6;              // 0..7
  const int row  = (int)blockIdx.x * 8 + wid;     // 1 wave = 1 row
  const int m0   = row & ~(M_EV - 1);
  const int mloc = row & (M_EV - 1);

  __shared__ float4 s_sp[M_EV];                   // 64 KB
  __shared__ int    s_ci[8][CAND_CAP];
  __shared__ float  s_cd[8][CAND_CAP];
  __shared__ int    s_wi[8][K_NN];
  __shared__ float  s_ww[8][K_NN];

  // stage event slab: 4096 float4 by 512 threads
  {
    const float4* src = space + m0;
    #pragma unroll
    for (int t = 0; t < 8; ++t) {
      const int i = (int)threadIdx.x + t * 512;
      s_sp[i] = src[i];
    }
  }
  __syncthreads();

  const float4 rc = s_sp[mloc];                   // wave-uniform broadcast

  // --- pass A: running per-lane min (single live register) ---
  float m = INFINITY;
  #pragma unroll
  for (int t = 0; t < 64; ++t) {
    const float4 c = s_sp[lane + (t << 6)];
    const float dx = rc.x - c.x, dy = rc.y - c.y;
    const float dz = rc.z - c.z, dw = rc.w - c.w;
    m = fminf(m, fmaf(dx, dx, fmaf(dy, dy, fmaf(dz, dz, dw * dw))));
  }

  // --- bitonic sort of lane minima (ascending), straight-line ---
  float ms = m;
  #pragma unroll
  for (int k = 2; k <= 64; k <<= 1) {
    #pragma unroll
    for (int j = k >> 1; j > 0; j >>= 1) {
      const float o = __shfl_xor(ms, j);
      const bool keepmin = (((lane & j) == 0) == ((lane & k) == 0));
      ms = keepmin ? fminf(ms, o) : fmaxf(ms, o);
    }
  }
  const float Tub = __shfl(ms, 31);     // 32nd-smallest lane-min >= true kth

  // --- pass B: recompute + ballot-compact survivors (ascending index) ---
  int C;
  {
    int base = 0;
    #pragma unroll
    for (int t = 0; t < 64; ++t) {
      const float4 c = s_sp[lane + (t << 6)];
      const float dx = rc.x - c.x, dy = rc.y - c.y;
      const float dz = rc.z - c.z, dw = rc.w - c.w;
      const float dd = fmaf(dx, dx, fmaf(dy, dy, fmaf(dz, dz, dw * dw)));
      const bool p = (dd <= Tub);
      const unsigned long long mk = __ballot(p);
      if (p) {
        const int pos = base + mbcnt64(mk);
        if (pos < CAND_CAP) { s_ci[wid][pos] = (t << 6) + lane; s_cd[wid][pos] = dd; }
      }
      base += (int)__popcll(mk);
    }
    C = base;
  }

  if (C > CAND_CAP) {
    // --- cold exact fallback: bisect with LDS recompute ---
    unsigned lo = 0u, hi = __float_as_uint(Tub);
    while (lo < hi) {
      const unsigned mid = (lo + hi) >> 1;
      const float fm = __uint_as_float(mid);
      int c = 0;
      for (int t = 0; t < 64; ++t) {
        const float4 cc = s_sp[lane + (t << 6)];
        const float dx = rc.x - cc.x, dy = rc.y - cc.y;
        const float dz = rc.z - cc.z, dw = rc.w - cc.w;
        const float dd = fmaf(dx, dx, fmaf(dy, dy, fmaf(dz, dz, dw * dw)));
        c += (int)__popcll(__ballot(dd <= fm));
      }
      if (c >= K_NN) { hi = mid; if (c == K_NN) break; }
      else lo = mid + 1;
    }
    const float T = __uint_as_float(hi);
    int base = 0;
    for (int pass = 0; pass < 2; ++pass) {     // 0: strict-less, 1: equal
      for (int t = 0; t < 64; ++t) {
        const float4 cc = s_sp[lane + (t << 6)];
        const float dx = rc.x - cc.x, dy = rc.y - cc.y;
        const float dz = rc.z - cc.z, dw = rc.w - cc.w;
        const float dd = fmaf(dx, dx, fmaf(dy, dy, fmaf(dz, dz, dw * dw)));
        const bool p = pass ? (dd == T) : (dd < T);
        const unsigned long long mk = __ballot(p);
        if (p) {
          const int pos = base + mbcnt64(mk);
          if (pos < CAND_CAP) { s_ci[wid][pos] = (t << 6) + lane; s_cd[wid][pos] = dd; }
        }
        base += (int)__popcll(mk);
      }
    }
    C = base < CAND_CAP ? base : CAND_CAP;
  }

  // --- tail: exact top-32 among C (<=128) candidates, 2 per lane ---
  const bool h0 = lane < C, h1 = (64 + lane) < C;
  const float v0 = h0 ? s_cd[wid][lane]      : INFINITY;
  const float v1 = h1 ? s_cd[wid][64 + lane] : INFINITY;
  const int   i0 = h0 ? s_ci[wid][lane]      : 0;
  const int   i1 = h1 ? s_ci[wid][64 + lane] : 0;

  unsigned lo = 0u, hi = __float_as_uint(Tub);
  while (lo < hi) {
    const unsigned mid = (lo + hi) >> 1;
    const float fm = __uint_as_float(mid);
    const int c = (int)__popcll(__ballot(v0 <= fm)) +
                  (int)__popcll(__ballot(v1 <= fm));
    if (c >= K_NN) { hi = mid; if (c == K_NN) break; }
    else lo = mid + 1;
  }
  const float T2 = __uint_as_float(hi);

  // stable selection: all strict-less, then lowest-position equals
  const unsigned long long mkE0 = __ballot(v0 == T2);
  const unsigned long long mkE1 = __ballot(v1 == T2);
  const int L = (int)__popcll(__ballot(v0 < T2)) +
                (int)__popcll(__ballot(v1 < T2));
  const int e = K_NN - L;                        // equals to take (>=0)
  const int nE0 = (int)__popcll(mkE0);
  const bool sel0 = (v0 < T2) || ((v0 == T2) && (mbcnt64(mkE0) < e));
  const bool sel1 = (v1 < T2) || ((v1 == T2) && (nE0 + mbcnt64(mkE1) < e));

  const float w0 = __expf(-10.f * v0);
  const float w1 = __expf(-10.f * v1);

  {
    const unsigned long long mkS0 = __ballot(sel0);
    if (sel0) {
      const int pos = mbcnt64(mkS0);
      s_wi[wid][pos] = i0; s_ww[wid][pos] = w0;
    }
    const int b0 = (int)__popcll(mkS0);
    const unsigned long long mkS1 = __ballot(sel1);
    if (sel1) {
      const int pos = b0 + mbcnt64(mkS1);
      s_wi[wid][pos] = i1; s_ww[wid][pos] = w1;
    }
  }

  // --- aggregation: lane = feature, 32 winners ---
  float accm = 0.f;
  float accx = -INFINITY;
  const float* __restrict__ pb = prop + ((size_t)m0 << 6) + lane;
  #pragma unroll 8
  for (int n = 0; n < K_NN; ++n) {
    const int   j = s_wi[wid][n];               // uniform LDS broadcast
    const float w = s_ww[wid][n];
    const float v = pb[(size_t)j << 6];         // coalesced 256B, L2-hot
    const float wv = w * v;
    accm += wv;
    accx = fmaxf(accx, wv);
  }
  out[(size_t)row * 128 + lane]      = accm * (1.f / K_NN);
  out[(size_t)row * 128 + 64 + lane] = accx;
}

// ---------------------------------------------------------------------------
extern "C" void kernel_launch(void* const* d_in, const int* in_sizes, int n_in,
                              void* d_out, int out_size, void* d_ws, size_t ws_size,
                              hipStream_t stream) {
  const float* x  = (const float*)d_in[0];
  const float* Ws = (const float*)d_in[1];
  const float* bs = (const float*)d_in[2];
  const float* Wp = (const float*)d_in[3];
  const float* bp = (const float*)d_in[4];
  float* out = (float*)d_out;

  // workspace layout: prop [N,64] f32 (4 MB) | space [N,4] f32 (256 KB)
  float* prop  = (float*)d_ws;
  float* space = (float*)((char*)d_ws + (size_t)N_TOT * PROP_D * sizeof(float));

  linear_kernel<<<N_TOT / 16, 256, 0, stream>>>(x, Ws, bs, Wp, bp, space, prop);
  knn_kernel<<<N_TOT / 8, 512, 0, stream>>>((const float4*)space, prop, out);
}